// Round 6
// baseline (279.008 us; speedup 1.0000x reference)
//
#include <hip/hip_runtime.h>
#include <hip/hip_bf16.h>
#include <cstdint>
#include <cstddef>

namespace {

constexpr int BATCH = 16;
constexpr int LEN   = 8192;
constexpr int CIN   = 257;
constexpr int CS    = 256;   // space channels
constexpr int NF    = 4096;  // output frames
constexpr int KG    = 1280;  // GEMM K (5 taps * 256 ch), time handled as rank-1
constexpr int NITER = 20;    // K tiles of 64
constexpr int LPAD  = LEN + 4;   // 8196 padded rows per batch

// ---- tier-1 workspace layout (8-phase path): xs bf16 + rowsq + wt + w0
constexpr size_t XS_BYTES  = (size_t)BATCH * LPAD * CS * 2;   // 67,141,632
constexpr size_t RSQ_OFF   = XS_BYTES;
constexpr size_t RSQ_BYTES = (size_t)BATCH * LPAD * 4;        // 524,544
constexpr size_t WT1_OFF   = RSQ_OFF + RSQ_BYTES;
constexpr size_t W01_OFF   = WT1_OFF + (size_t)CS * KG * 2;
constexpr size_t WS1_NEED  = W01_OFF + (size_t)CS * 4;        // ~68.3 MB

// ---- tier-2 workspace layout (fused path): wt + w0 only (~0.66 MB)
constexpr size_t W02_OFF  = (size_t)CS * KG * 2;
constexpr size_t WS2_NEED = W02_OFF + (size_t)CS * 4;

typedef __attribute__((ext_vector_type(8))) short short8;
typedef __attribute__((ext_vector_type(8))) unsigned short ushort8v;
typedef __attribute__((ext_vector_type(4))) float f32x4;

__device__ __forceinline__ unsigned short f2bf_bits(float f) {
  union { __hip_bfloat16 h; unsigned short u; } cv;
  cv.h = __float2bfloat16(f);
  return cv.u;
}

__device__ __forceinline__ void async_cp16(const void* g, void* l) {
  __builtin_amdgcn_global_load_lds(
      (const __attribute__((address_space(1))) void*)g,
      (__attribute__((address_space(3))) void*)l,
      16, 0, 0);
}

} // namespace

// ---------------- prep: W (257x1281 f32) -> wt bf16 [256][1280] + w0[256] f32
__global__ void prep_w_kernel(const float* __restrict__ W,
                              __hip_bfloat16* __restrict__ wt,
                              float* __restrict__ w0) {
  int n = blockIdx.x;                    // 0..255 -> out channel n+1
  const float* wrow = W + (size_t)(n + 1) * 1281;
  for (int k = threadIdx.x; k < KG; k += blockDim.x)
    wt[(size_t)n * KG + k] = __float2bfloat16(wrow[1 + k]);
  if (threadIdx.x == 0) w0[n] = wrow[0];
}

// ---------------- prep x: f32 -> bf16 padded rows + per-row sumsq (f32)
// block = 256 threads handles 16 rows = 4112 floats (16B aligned).
__global__ void prep_x_kernel(const float* __restrict__ x,
                              __hip_bfloat16* __restrict__ xs,
                              float* __restrict__ rowsq) {
  const int tid = threadIdx.x;
  const int bx  = blockIdx.x;
  if (bx < 8192) {
    __shared__ float4 xf4[1028];
    const float4* src = (const float4*)(x + (size_t)bx * 4112);
#pragma unroll
    for (int i = 0; i < 4; ++i) {
      int idx = i * 256 + tid;
      xf4[idx] = src[idx];
    }
    if (tid < 4) xf4[1024 + tid] = src[1024 + tid];
    __syncthreads();
    const float* xf = (const float*)xf4;
    const int row = tid >> 4, seg = tid & 15;
    const float* v = xf + row * 257 + 1 + seg * 16;
    float ss = 0.f;
    unsigned short u[16];
#pragma unroll
    for (int i = 0; i < 16; ++i) {
      float f = v[i];
      ss += f * f;
      u[i] = f2bf_bits(f);
    }
    const int b = bx >> 9;
    const int t = (bx & 511) * 16 + row;
    const size_t tpg = (size_t)b * LPAD + 2 + t;
    ushort8v* dst = (ushort8v*)((unsigned short*)xs + tpg * CS + seg * 16);
    ushort8v p0, p1;
#pragma unroll
    for (int i = 0; i < 8; ++i) { p0[i] = u[i]; p1[i] = u[8 + i]; }
    dst[0] = p0;
    dst[1] = p1;
    ss += __shfl_xor(ss, 1);
    ss += __shfl_xor(ss, 2);
    ss += __shfl_xor(ss, 4);
    ss += __shfl_xor(ss, 8);
    if (seg == 0) rowsq[tpg] = ss;
  } else {
    // zero the 64 pad rows (4 per batch) + their rowsq
    for (int i = tid; i < 64 * 128; i += 256) {
      int row = i >> 7, uo = i & 127;
      int b = row >> 2, j = row & 3;
      size_t tpg = (size_t)b * LPAD + (j < 2 ? j : 8192 + j);  // 0,1,8194,8195
      ((uint32_t*)xs)[tpg * 128 + uo] = 0;
      if (uo == 0) rowsq[tpg] = 0.0f;
    }
  }
}

// ---------------- tier-1 GEMM: m201-style 8-phase, BM=256 BN=256 BK=64
// 8 waves (wr in 0..1 = 128-row half, wc in 0..3 = 64-col quarter), wave tile
// 128x64, acc 8x4 f32x4 (128 AGPR). A dbuf (staged t+1 at P1/P2), B TRIPLE
// buf (staged t+2 at P3/P4); boundary s_waitcnt vmcnt(4) leaves one full
// B-tile in flight (never 0 until tail). 2 barriers/phase, lgkmcnt(0)+
// sched_barrier before each MFMA cluster, setprio around it. LDS 160 KiB
// exactly; epilogue scratch aliases into it.
__global__ __launch_bounds__(512, 2) void lorentz_gemm8_kernel(
    const __hip_bfloat16* __restrict__ xs,
    const __hip_bfloat16* __restrict__ wt,
    const float* __restrict__ rowsq,
    const float* __restrict__ w0,
    const float* __restrict__ bvec,
    float* __restrict__ out) {
  __shared__ alignas(16) char lds[163840];  // A: 2x32K @0, B: 3x32K @64K

  const int tid   = threadIdx.x;
  const int w     = tid >> 6;   // 0..7
  const int lane  = tid & 63;
  const int row16 = lane & 15;
  const int q     = lane >> 4;  // 0..3
  const int wr    = w >> 2;     // 0..1  M-half (128 rows)
  const int wc    = w & 3;      // 0..3  N-quarter (64 cols)
  const int lg    = lane >> 3;  // staging row-in-group
  const int lc    = lane & 7;   // staging chunk
  const int csw   = lc ^ lg;    // XOR swizzle (pos p holds chunk p^(row&7))

  const int bx    = blockIdx.x;
  const int b     = bx >> 4;            // 16 M-tiles per batch
  const int Mblk  = (bx & 15) * 256;

  const __hip_bfloat16* xsb = xs + (size_t)b * LPAD * CS;

  f32x4 acc[8][4];
#pragma unroll
  for (int i = 0; i < 8; ++i)
#pragma unroll
    for (int j = 0; j < 4; ++j) acc[i][j] = (f32x4){0.f, 0.f, 0.f, 0.f};

  // staging: one 128-row half = 16KB; each wave covers rows w*16..+16 via 2
  // issues; DMA dest is wave-uniform base + lane*16 (linear), source carries
  // the chunk swizzle.
  auto stgA = [&](int t, int hf, char* buf) {
    char* dst = buf + hf * 16384 + w * 2048;
#pragma unroll
    for (int j = 0; j < 2; ++j) {
      const int r  = w * 16 + j * 8 + lg;               // 0..127
      const int rp = 2 * (Mblk + hf * 128 + r) + (t >> 2);  // padded row
      async_cp16(xsb + (size_t)rp * CS + ((t & 3) << 6) + csw * 8,
                 dst + j * 1024);
    }
  };
  auto stgB = [&](int t, int hf, char* buf) {
    char* dst = buf + hf * 16384 + w * 2048;
#pragma unroll
    for (int j = 0; j < 2; ++j) {
      const int n = hf * 128 + w * 16 + j * 8 + lg;     // 0..255
      async_cp16(wt + (size_t)n * KG + (t << 6) + csw * 8, dst + j * 1024);
    }
  };

  auto rdA = [&](const char* Ah, int mt, int s) -> short8 {
    const int lr = mt * 16 + row16;
    const int p  = (s * 4 + q) ^ lc;
    return *(const short8*)(Ah + ((lr * 8 + p) << 4));
  };
  auto rdB = [&](const char* Bh, int nt, int s) -> short8 {
    const int lr = (wc & 1) * 64 + nt * 16 + row16;
    const int p  = (s * 4 + q) ^ lc;
    return *(const short8*)(Bh + ((lr * 8 + p) << 4));
  };

  char* Acur = lds;
  char* Aalt = lds + 32768;
  char* Bcur = lds + 65536;
  char* Bnx  = lds + 65536 + 32768;
  char* Bnn  = lds + 65536 + 65536;

  // ---- prologue: B(0), A(0), B(1) issued; keep B(1) in flight ------------
  stgB(0, 0, Bcur); stgB(0, 1, Bcur);
  stgA(0, 0, Acur); stgA(0, 1, Acur);
  stgB(1, 0, Bnx);  stgB(1, 1, Bnx);
  asm volatile("s_waitcnt vmcnt(4)" ::: "memory");
  asm volatile("" ::: "memory");
  __builtin_amdgcn_s_barrier();
  asm volatile("" ::: "memory");

  // ---- main loop: 4 phases per K-tile --------------------------------------
  for (int t = 0; t < NITER; ++t) {
    const char* Ah = Acur + (wr << 14);
    const char* Bh = Bcur + ((wc >> 1) << 14);
    short8 bfr[4];
#pragma unroll
    for (int p = 0; p < 4; ++p) {
      const int s  = p >> 1;
      const int mb = (p & 1) << 2;
      short8 afr[4];
      if ((p & 1) == 0) {
#pragma unroll
        for (int nt = 0; nt < 4; ++nt) bfr[nt] = rdB(Bh, nt, s);
      }
#pragma unroll
      for (int i = 0; i < 4; ++i) afr[i] = rdA(Ah, mb + i, s);
      if (p == 0 && t + 1 < NITER) stgA(t + 1, 0, Aalt);
      if (p == 1 && t + 1 < NITER) stgA(t + 1, 1, Aalt);
      if (p == 2 && t + 2 < NITER) stgB(t + 2, 0, Bnn);
      if (p == 3 && t + 2 < NITER) stgB(t + 2, 1, Bnn);
      asm volatile("" ::: "memory");
      __builtin_amdgcn_s_barrier();
      asm volatile("s_waitcnt lgkmcnt(0)" ::: "memory");
      __builtin_amdgcn_sched_barrier(0);
      __builtin_amdgcn_s_setprio(1);
#pragma unroll
      for (int i = 0; i < 4; ++i)
#pragma unroll
        for (int nt = 0; nt < 4; ++nt)
          acc[mb + i][nt] = __builtin_amdgcn_mfma_f32_16x16x32_bf16(
              afr[i], bfr[nt], acc[mb + i][nt], 0, 0, 0);
      __builtin_amdgcn_s_setprio(0);
      __builtin_amdgcn_sched_barrier(0);
      if (p == 3) {
        if (t + 2 < NITER) { asm volatile("s_waitcnt vmcnt(4)" ::: "memory"); }
        else               { asm volatile("s_waitcnt vmcnt(0)" ::: "memory"); }
      }
      asm volatile("" ::: "memory");
      __builtin_amdgcn_s_barrier();
      asm volatile("" ::: "memory");
    }
    // rotate buffers
    char* tA = Acur; Acur = Aalt; Aalt = tA;
    char* tB = Bcur; Bcur = Bnx; Bnx = Bnn; Bnn = tB;
  }

  // ---- epilogue: time0 (rowsq) + bias, renorm across 256 ch, store --------
  __syncthreads();
  float* time0_s  = (float*)lds;            // 256 f32 (aliases A buffers)
  float* normsq_s = (float*)(lds + 1024);   // 256 f32
  if (tid < 256) {
    const float* rs = rowsq + (size_t)b * LPAD + 2 * (Mblk + tid);
    float s5 = rs[0] + rs[1] + rs[2] + rs[3] + rs[4];
    time0_s[tid]  = sqrtf(1.0f + s5);
    normsq_s[tid] = 0.0f;
  }
  __syncthreads();

  float w0v[4], bv[4];
#pragma unroll
  for (int nt = 0; nt < 4; ++nt) {
    int n = wc * 64 + nt * 16 + row16;
    w0v[nt] = w0[n];
    bv[nt]  = bvec[1 + n];
  }

#pragma unroll
  for (int mt = 0; mt < 8; ++mt) {
    f32x4 t4 = *(const f32x4*)&time0_s[wr * 128 + mt * 16 + q * 4];
#pragma unroll
    for (int nt = 0; nt < 4; ++nt)
#pragma unroll
      for (int r = 0; r < 4; ++r)
        acc[mt][nt][r] = acc[mt][nt][r] + t4[r] * w0v[nt] + bv[nt];
#pragma unroll
    for (int r = 0; r < 4; ++r) {
      float ps = 0.f;
#pragma unroll
      for (int nt = 0; nt < 4; ++nt) ps += acc[mt][nt][r] * acc[mt][nt][r];
      ps += __shfl_xor(ps, 1);
      ps += __shfl_xor(ps, 2);
      ps += __shfl_xor(ps, 4);
      ps += __shfl_xor(ps, 8);
      if (row16 == 0)
        atomicAdd(&normsq_s[wr * 128 + mt * 16 + q * 4 + r], ps);
    }
  }
  __syncthreads();

#pragma unroll
  for (int mt = 0; mt < 8; ++mt) {
#pragma unroll
    for (int r = 0; r < 4; ++r) {
      int m = wr * 128 + mt * 16 + q * 4 + r;
      float nsq  = normsq_s[m];
      float norm = sqrtf(nsq);
      float scale = fminf(1.0f, 1000.0f / fmaxf(norm, 1e-8f));
      size_t ob = ((size_t)b * NF + Mblk + m) * 257;
#pragma unroll
      for (int nt = 0; nt < 4; ++nt) {
        int n = wc * 64 + nt * 16 + row16;
        out[ob + 1 + n] = acc[mt][nt][r] * scale;
      }
    }
  }
  if (tid < 256) {
    float nsq  = normsq_s[tid];
    float norm = sqrtf(nsq);
    float scale = fminf(1.0f, 1000.0f / fmaxf(norm, 1e-8f));
    size_t ob = ((size_t)b * NF + Mblk + tid) * 257;
    out[ob] = sqrtf(1.0f + scale * scale * nsq);
  }
}

// ---------------- tier-2: fused GEMM (R1, verified 116us) -------------------
__global__ __launch_bounds__(512, 2) void lorentz_fused_kernel(
    const float* __restrict__ x,
    const __hip_bfloat16* __restrict__ wt,
    const float* __restrict__ w0,
    const float* __restrict__ bvec,
    float* __restrict__ out) {
  __shared__ alignas(16) char ldsA[2][16384];
  __shared__ alignas(16) char ldsB[2][32768];
  __shared__ alignas(16) float time0_s[128];
  __shared__ alignas(16) float normsq_s[128];

  const int tid   = threadIdx.x;
  const int w     = tid >> 6;
  const int lane  = tid & 63;
  const int row16 = lane & 15;
  const int q     = lane >> 4;
  const int mh    = w >> 2;
  const int nq    = w & 3;
  const int lg    = lane >> 3;
  const int lc    = lane & 7;
  const int csw   = lc ^ lg;

  const int bx    = blockIdx.x;
  const int b     = bx >> 5;
  const int Mblk  = (bx & 31) * 128;

  const int m0 = w * 16 + lg;
  const int m1 = m0 + 8;
  const float* xb = x + (size_t)b * LEN * CIN;

  f32x4 acc[4][4];
#pragma unroll
  for (int i = 0; i < 4; ++i)
#pragma unroll
    for (int j = 0; j < 4; ++j) acc[i][j] = (f32x4){0.f, 0.f, 0.f, 0.f};

  float ssq0 = 0.f, ssq1 = 0.f;
  f32x4 a00, a01, a10, a11;

  auto loadA = [&](int it) {
    const int kk = it >> 2;
    const int c0 = (it & 3) << 6;
    const int coff = 1 + c0 + lc * 8;
    const int t0 = 2 * (Mblk + m0) + kk - 2;
    const int t1 = t0 + 16;
    a00 = (f32x4){0.f, 0.f, 0.f, 0.f};
    a01 = a00; a10 = a00; a11 = a00;
    if ((unsigned)t0 < (unsigned)LEN) {
      const float* g = xb + (size_t)t0 * CIN + coff;
      __builtin_memcpy(&a00, g, 16);
      __builtin_memcpy(&a01, g + 4, 16);
    }
    if ((unsigned)t1 < (unsigned)LEN) {
      const float* g = xb + (size_t)t1 * CIN + coff;
      __builtin_memcpy(&a10, g, 16);
      __builtin_memcpy(&a11, g + 4, 16);
    }
  };

  auto writeA = [&](char* A) {
    ssq0 += a00[0]*a00[0] + a00[1]*a00[1] + a00[2]*a00[2] + a00[3]*a00[3]
          + a01[0]*a01[0] + a01[1]*a01[1] + a01[2]*a01[2] + a01[3]*a01[3];
    ssq1 += a10[0]*a10[0] + a10[1]*a10[1] + a10[2]*a10[2] + a10[3]*a10[3]
          + a11[0]*a11[0] + a11[1]*a11[1] + a11[2]*a11[2] + a11[3]*a11[3];
    ushort8v u0, u1;
#pragma unroll
    for (int i = 0; i < 4; ++i) {
      u0[i]     = f2bf_bits(a00[i]);
      u0[4 + i] = f2bf_bits(a01[i]);
      u1[i]     = f2bf_bits(a10[i]);
      u1[4 + i] = f2bf_bits(a11[i]);
    }
    *(ushort8v*)(A + ((m0 * 8 + csw) << 4)) = u0;
    *(ushort8v*)(A + ((m1 * 8 + csw) << 4)) = u1;
  };

  auto stageB = [&](int it, char* B) {
    const int k0 = it << 6;
#pragma unroll
    for (int j = 0; j < 4; ++j) {
      const int n = w * 32 + j * 8 + lg;
      async_cp16(wt + (size_t)n * KG + k0 + csw * 8, B + (w * 4 + j) * 1024);
    }
  };

  auto compute = [&](const char* A, const char* B) {
#pragma unroll
    for (int s = 0; s < 2; ++s) {
      const int p = (s * 4 + q) ^ lc;
      short8 bfr[4];
#pragma unroll
      for (int nt = 0; nt < 4; ++nt)
        bfr[nt] = *(const short8*)(B + (((nq * 64 + nt * 16 + row16) * 8 + p) << 4));
#pragma unroll
      for (int mt = 0; mt < 4; ++mt) {
        short8 af = *(const short8*)(A + (((mh * 64 + mt * 16 + row16) * 8 + p) << 4));
#pragma unroll
        for (int nt = 0; nt < 4; ++nt)
          acc[mt][nt] = __builtin_amdgcn_mfma_f32_16x16x32_bf16(
              af, bfr[nt], acc[mt][nt], 0, 0, 0);
      }
    }
  };

  loadA(0);
  stageB(0, ldsB[0]);
  asm volatile("s_waitcnt vmcnt(4)" ::: "memory");
  writeA(ldsA[0]);
  loadA(1);
  asm volatile("s_waitcnt lgkmcnt(0)" ::: "memory");

  for (int it = 0; it < NITER; ++it) {
    char* Ac = ldsA[it & 1];
    char* Bc = ldsB[it & 1];
    if (it < NITER - 1) {
      char* An = ldsA[(it + 1) & 1];
      char* Bn = ldsB[(it + 1) & 1];
      stageB(it + 1, Bn);
      asm volatile("s_waitcnt vmcnt(4)" ::: "memory");
      writeA(An);
      if (it < NITER - 2) loadA(it + 2);
    } else {
      asm volatile("s_waitcnt vmcnt(0)" ::: "memory");
    }
    asm volatile("" ::: "memory");
    __builtin_amdgcn_s_barrier();
    asm volatile("" ::: "memory");
    compute(Ac, Bc);
    asm volatile("" ::: "memory");
    __builtin_amdgcn_s_barrier();
    asm volatile("" ::: "memory");
  }

  __syncthreads();
  if (tid < 128) normsq_s[tid] = 0.0f;
  {
    float s0 = ssq0;
    s0 += __shfl_xor(s0, 1); s0 += __shfl_xor(s0, 2); s0 += __shfl_xor(s0, 4);
    float s1 = ssq1;
    s1 += __shfl_xor(s1, 1); s1 += __shfl_xor(s1, 2); s1 += __shfl_xor(s1, 4);
    if (lc == 0) {
      time0_s[m0] = sqrtf(1.0f + s0);
      time0_s[m1] = sqrtf(1.0f + s1);
    }
  }
  __syncthreads();

  float w0v[4], bv[4];
#pragma unroll
  for (int nt = 0; nt < 4; ++nt) {
    int n = nq * 64 + nt * 16 + row16;
    w0v[nt] = w0[n];
    bv[nt]  = bvec[1 + n];
  }

#pragma unroll
  for (int mt = 0; mt < 4; ++mt) {
    f32x4 t4 = *(const f32x4*)&time0_s[mh * 64 + mt * 16 + q * 4];
#pragma unroll
    for (int nt = 0; nt < 4; ++nt)
#pragma unroll
      for (int r = 0; r < 4; ++r)
        acc[mt][nt][r] = acc[mt][nt][r] + t4[r] * w0v[nt] + bv[nt];
#pragma unroll
    for (int r = 0; r < 4; ++r) {
      float ps = 0.f;
#pragma unroll
      for (int nt = 0; nt < 4; ++nt) ps += acc[mt][nt][r] * acc[mt][nt][r];
      ps += __shfl_xor(ps, 1);
      ps += __shfl_xor(ps, 2);
      ps += __shfl_xor(ps, 4);
      ps += __shfl_xor(ps, 8);
      if (row16 == 0) atomicAdd(&normsq_s[mh * 64 + mt * 16 + q * 4 + r], ps);
    }
  }
  __syncthreads();

#pragma unroll
  for (int mt = 0; mt < 4; ++mt) {
#pragma unroll
    for (int r = 0; r < 4; ++r) {
      int m = mh * 64 + mt * 16 + q * 4 + r;
      float nsq  = normsq_s[m];
      float norm = sqrtf(nsq);
      float scale = fminf(1.0f, 1000.0f / fmaxf(norm, 1e-8f));
      size_t ob = ((size_t)b * NF + Mblk + m) * 257;
#pragma unroll
      for (int nt = 0; nt < 4; ++nt) {
        int n = nq * 64 + nt * 16 + row16;
        out[ob + 1 + n] = acc[mt][nt][r] * scale;
      }
    }
  }
  if (tid < 128) {
    float nsq  = normsq_s[tid];
    float norm = sqrtf(nsq);
    float scale = fminf(1.0f, 1000.0f / fmaxf(norm, 1e-8f));
    size_t ob = ((size_t)b * NF + Mblk + tid) * 257;
    out[ob] = sqrtf(1.0f + scale * scale * nsq);
  }
}

// ---------------- tier-3: naive fp32 fallback
__global__ void fallback_kernel(const float* __restrict__ x,
                                const float* __restrict__ W,
                                const float* __restrict__ bvec,
                                float* __restrict__ out) {
  int fid = blockIdx.x;
  int b = fid >> 12;
  int g = fid & (NF - 1);
  __shared__ float patch[1280];
  __shared__ float red[256];
  int tid = threadIdx.x;
  float ss = 0.f;
  for (int k = tid; k < 1280; k += 256) {
    int kk = k >> 8, c = k & 255;
    int t = 2 * g + kk - 2;
    float v = (t >= 0 && t < LEN) ? x[((size_t)b * LEN + t) * CIN + 1 + c] : 0.f;
    patch[k] = v;
    ss += v * v;
  }
  red[tid] = ss;
  __syncthreads();
  for (int off = 128; off > 0; off >>= 1) {
    if (tid < off) red[tid] += red[tid + off];
    __syncthreads();
  }
  float time0 = sqrtf(1.f + red[0]);
  __syncthreads();
  const float* wrow = W + (size_t)(tid + 1) * 1281;
  float acc = time0 * wrow[0] + bvec[tid + 1];
  for (int k = 0; k < 1280; ++k) acc += wrow[1 + k] * patch[k];
  red[tid] = acc * acc;
  __syncthreads();
  for (int off = 128; off > 0; off >>= 1) {
    if (tid < off) red[tid] += red[tid + off];
    __syncthreads();
  }
  float nsq = red[0];
  float norm = sqrtf(nsq);
  float scale = fminf(1.f, 1000.f / fmaxf(norm, 1e-8f));
  size_t ob = ((size_t)b * NF + g) * 257;
  out[ob + 1 + tid] = acc * scale;
  if (tid == 0) out[ob] = sqrtf(1.f + scale * scale * nsq);
}

extern "C" void kernel_launch(void* const* d_in, const int* in_sizes, int n_in,
                              void* d_out, int out_size, void* d_ws, size_t ws_size,
                              hipStream_t stream) {
  const float* x  = (const float*)d_in[0];
  const float* W  = (const float*)d_in[1];
  const float* bv = (const float*)d_in[2];
  float* out = (float*)d_out;
  char* ws = (char*)d_ws;

  if (ws_size >= WS1_NEED) {
    __hip_bfloat16* xs = (__hip_bfloat16*)ws;
    float* rowsq       = (float*)(ws + RSQ_OFF);
    __hip_bfloat16* wt = (__hip_bfloat16*)(ws + WT1_OFF);
    float* w0          = (float*)(ws + W01_OFF);
    prep_w_kernel<<<256, 256, 0, stream>>>(W, wt, w0);
    prep_x_kernel<<<8193, 256, 0, stream>>>(x, xs, rowsq);
    lorentz_gemm8_kernel<<<BATCH * (NF / 256), 512, 0, stream>>>(
        xs, wt, rowsq, w0, bv, out);
  } else if (ws_size >= WS2_NEED) {
    __hip_bfloat16* wt = (__hip_bfloat16*)ws;
    float* w0          = (float*)(ws + W02_OFF);
    prep_w_kernel<<<256, 256, 0, stream>>>(W, wt, w0);
    lorentz_fused_kernel<<<BATCH * (NF / 128), 512, 0, stream>>>(
        x, wt, w0, bv, out);
  } else {
    fallback_kernel<<<BATCH * NF, 256, 0, stream>>>(x, W, bv, out);
  }
}